// Round 12
// baseline (371.683 us; speedup 1.0000x reference)
//
#include <hip/hip_runtime.h>

#define N_EDGES  800000
#define N_NODES  50000
#define IN_DIM   64
#define EDGE_DIM 32
#define HID      96
#define OUT_DIM  64
#define BE       128              // edges per tile
#define PAD      104              // LDS row stride (bf16): 208 B
#define NTILES   (N_EDGES / BE)   // 6250 exactly
#define THREADS  512
#define GRID     768              // 3 blocks/CU, persistent (LDS 46.6 KB)
#define SCAN_B   1024
#define SCAN_NB  ((N_NODES + SCAN_B - 1) / SCAN_B)   // 49

typedef __attribute__((ext_vector_type(8))) short  short8;
typedef __attribute__((ext_vector_type(4))) ushort bf16x4;
typedef __attribute__((ext_vector_type(4))) float  f32x4;

__device__ inline ushort f2bf(float f) {
    union { float f; unsigned u; } v; v.f = f;
    unsigned r = v.u + 0x7FFFu + ((v.u >> 16) & 1u);   // round-to-nearest-even
    return (ushort)(r >> 16);
}
__device__ inline float b2f(ushort u) {
    union { unsigned u; float f; } v; v.u = ((unsigned)u) << 16;
    return v.f;
}

// ---------------------------------------------------------------------------
// CSR-build kernels
// ---------------------------------------------------------------------------
__global__ __launch_bounds__(256) void hist_kernel(const int* __restrict__ ei,
                                                   int* __restrict__ hist) {
    int e = blockIdx.x * 256 + threadIdx.x;
    if (e < N_EDGES) atomicAdd(&hist[ei[N_EDGES + e]], 1);
}

__global__ __launch_bounds__(SCAN_B) void scan1_kernel(const int* __restrict__ hist,
                                                       int* __restrict__ starts,
                                                       int* __restrict__ bsums) {
    __shared__ int buf[2][SCAN_B];
    const int tid = threadIdx.x;
    const int gid = blockIdx.x * SCAN_B + tid;
    int v = (gid < N_NODES) ? hist[gid] : 0;
    int cur = 0;
    buf[0][tid] = v;
    __syncthreads();
    #pragma unroll
    for (int off = 1; off < SCAN_B; off <<= 1) {
        int t = buf[cur][tid] + ((tid >= off) ? buf[cur][tid - off] : 0);
        buf[cur ^ 1][tid] = t;
        __syncthreads();
        cur ^= 1;
    }
    int incl = buf[cur][tid];
    if (gid < N_NODES) starts[gid] = incl;
    if (tid == SCAN_B - 1) bsums[blockIdx.x] = incl;
}

__global__ __launch_bounds__(SCAN_B) void scan3_kernel(const int* __restrict__ hist,
                                                       int* __restrict__ starts,
                                                       int* __restrict__ cursor,
                                                       const int* __restrict__ bsums) {
    __shared__ int s_off;
    if (threadIdx.x < 64) {
        int v = ((int)threadIdx.x < (int)blockIdx.x) ? bsums[threadIdx.x] : 0;
        #pragma unroll
        for (int o = 32; o >= 1; o >>= 1) v += __shfl_xor(v, o, 64);
        if (threadIdx.x == 0) s_off = v;
    }
    __syncthreads();
    const int gid = blockIdx.x * SCAN_B + threadIdx.x;
    if (gid < N_NODES) {
        int e = starts[gid] - hist[gid] + s_off;
        starts[gid] = e;
        cursor[gid] = e;
    }
}

__global__ __launch_bounds__(256) void fill_kernel(const int* __restrict__ ei,
                                                   int* __restrict__ cursor,
                                                   int* __restrict__ epos) {
    int e = blockIdx.x * 256 + threadIdx.x;
    if (e < N_EDGES) {
        int c = ei[N_EDGES + e];
        int p = atomicAdd(&cursor[c], 1);
        epos[e] = p;
    }
}

// ---------------------------------------------------------------------------
// Fallback-path helpers
// ---------------------------------------------------------------------------
__global__ __launch_bounds__(256) void zero_kernel(float* __restrict__ out,
                                                   float* __restrict__ cnt) {
    int i = blockIdx.x * 256 + threadIdx.x;
    if (i < N_NODES * OUT_DIM) out[i] = 0.0f;
    if (i < N_NODES) cnt[i] = 0.0f;
}

__global__ __launch_bounds__(256) void div_kernel(float* __restrict__ out,
                                                  const float* __restrict__ cnt) {
    int i = blockIdx.x * 256 + threadIdx.x;
    if (i < N_NODES * OUT_DIM) {
        float c = cnt[i / OUT_DIM];
        out[i] = out[i] / fmaxf(c, 1.0f);
    }
}

// ---------------------------------------------------------------------------
// Fused gather -> bf16 MFMA MLP (r8 structure, LDS-overlay for occupancy).
// W2T is staged into sA rows 0..63 (sA unused until first gather), hoisted
// to registers, then sA is reused by the tile loop. LDS 59.9 -> 46.6 KB
// => 3 blocks/CU, 24 waves/CU (was 16).
// ATOMIC=true: atomic scatter fallback. ATOMIC=false: store per-edge output
// row (bf16, 128 B) at its CSR slot epos[e] in temp -> pull reads sequential.
// ---------------------------------------------------------------------------
template <bool ATOMIC>
__global__ __launch_bounds__(THREADS, 6) void edge_mlp_mfma_kernel(
    const float* __restrict__ x,
    const int*   __restrict__ ei,     // [2, E] int32
    const float* __restrict__ ea,
    const float* __restrict__ W1,     // [HID, HID] row-major (k, n)
    const float* __restrict__ b1,
    const float* __restrict__ W2,     // [HID, OUT] row-major (k, n)
    const float* __restrict__ b2,
    float*       __restrict__ out,    // [N, OUT] accumulator (ATOMIC only)
    float*       __restrict__ cnt,    // [N] (ATOMIC only)
    ushort*      __restrict__ temp,   // [E, OUT] bf16 (!ATOMIC only)
    const int*   __restrict__ epos)   // [E] CSR slot (!ATOMIC only)
{
    __shared__ ushort sA[BE][PAD];    // W2T staging (rows 0..63) -> tile buffer
    __shared__ ushort sW1T[HID][PAD]; // W1 transposed: [n][k]

    const int tid  = threadIdx.x;
    const int wave = tid >> 6;
    const int lane = tid & 63;
    const int lr   = lane & 15;
    const int lg   = lane >> 4;
    const int el_base = wave * 16;
    const int el   = el_base + (lane >> 2);   // gather/store row owned by this lane
    const int part = lane & 3;

    // ---- stage weights (bf16, transposed), float4-vectorized ----
    #pragma unroll 2
    for (int i = tid; i < HID * HID / 4; i += THREADS) {
        float4 v = reinterpret_cast<const float4*>(W1)[i];
        int k = (i * 4) / HID, n = (i * 4) % HID;
        sW1T[n + 0][k] = f2bf(v.x); sW1T[n + 1][k] = f2bf(v.y);
        sW1T[n + 2][k] = f2bf(v.z); sW1T[n + 3][k] = f2bf(v.w);
    }
    #pragma unroll 2
    for (int i = tid; i < HID * OUT_DIM / 4; i += THREADS) {   // W2T -> sA rows 0..63
        float4 v = reinterpret_cast<const float4*>(W2)[i];
        int k = (i * 4) / OUT_DIM, n = (i * 4) % OUT_DIM;
        sA[n + 0][k] = f2bf(v.x); sA[n + 1][k] = f2bf(v.y);
        sA[n + 2][k] = f2bf(v.z); sA[n + 3][k] = f2bf(v.w);
    }
    float rb1[6], rb2[4];
    #pragma unroll
    for (int nt = 0; nt < 6; ++nt) rb1[nt] = b1[nt * 16 + lr];
    #pragma unroll
    for (int nt = 0; nt < 4; ++nt) rb2[nt] = b2[nt * 16 + lr];
    __syncthreads();

    // ---- hoist W2 fragments to registers from the sA staging area ----
    short8 bw2[4][3];
    #pragma unroll
    for (int nt = 0; nt < 4; ++nt)
        #pragma unroll
        for (int ks = 0; ks < 3; ++ks)
            bw2[nt][ks] = *(const short8*)&sA[nt * 16 + lr][ks * 32 + lg * 8];
    __syncthreads();   // all waves hoisted before sA is overwritten by gathers

    // ---- prologue: prefetch first tile into registers ----
    float4 px0, px1, px2, px3, pe0, pe1;
    int ppos = 0, pdst = 0;
    int tl = blockIdx.x;
    {
        const int e = tl * BE + el;
        const int src = ei[e];
        if constexpr (ATOMIC) pdst = ei[N_EDGES + e];
        else                  ppos = epos[e];
        const float4* xp = reinterpret_cast<const float4*>(x) + (size_t)src * 16;
        const float4* ep = reinterpret_cast<const float4*>(ea) + (size_t)e * 8;
        px0 = xp[part]; px1 = xp[part + 4]; px2 = xp[part + 8]; px3 = xp[part + 12];
        pe0 = ep[part]; pe1 = ep[part + 4];
    }

    for (; tl < NTILES; tl += GRID) {
        // ---- write the prefetched tile into sA (f = part + 4*i) ----
        {
            bf16x4 w;
            w = bf16x4{ f2bf(px0.x), f2bf(px0.y), f2bf(px0.z), f2bf(px0.w) };
            *(bf16x4*)&sA[el][(part +  0) * 4] = w;
            w = bf16x4{ f2bf(px1.x), f2bf(px1.y), f2bf(px1.z), f2bf(px1.w) };
            *(bf16x4*)&sA[el][(part +  4) * 4] = w;
            w = bf16x4{ f2bf(px2.x), f2bf(px2.y), f2bf(px2.z), f2bf(px2.w) };
            *(bf16x4*)&sA[el][(part +  8) * 4] = w;
            w = bf16x4{ f2bf(px3.x), f2bf(px3.y), f2bf(px3.z), f2bf(px3.w) };
            *(bf16x4*)&sA[el][(part + 12) * 4] = w;
            w = bf16x4{ f2bf(pe0.x), f2bf(pe0.y), f2bf(pe0.z), f2bf(pe0.w) };
            *(bf16x4*)&sA[el][(part + 16) * 4] = w;
            w = bf16x4{ f2bf(pe1.x), f2bf(pe1.y), f2bf(pe1.z), f2bf(pe1.w) };
            *(bf16x4*)&sA[el][(part + 20) * 4] = w;
        }
        const int cpos = ppos, cdst = pdst;
        if constexpr (ATOMIC) {
            if (part == 0) atomicAdd(cnt + cdst, 1.0f);
        }

        // ---- prefetch next tile (flies during the GEMM section) ----
        const int tn = tl + GRID;
        const bool have = (tn < NTILES);
        float4 nx0, nx1, nx2, nx3, ne0, ne1;
        int npos = 0, ndst = 0;
        if (have) {
            const int e = tn * BE + el;
            const int src = ei[e];
            if constexpr (ATOMIC) ndst = ei[N_EDGES + e];
            else                  npos = epos[e];
            const float4* xp = reinterpret_cast<const float4*>(x) + (size_t)src * 16;
            const float4* ep = reinterpret_cast<const float4*>(ea) + (size_t)e * 8;
            nx0 = xp[part]; nx1 = xp[part + 4]; nx2 = xp[part + 8]; nx3 = xp[part + 12];
            ne0 = ep[part]; ne1 = ep[part + 4];
        }

        asm volatile("s_waitcnt lgkmcnt(0)" ::: "memory");
        __builtin_amdgcn_sched_barrier(0);

        // ---- GEMM1: H = relu(A @ W1 + b1) ----
        short8 af[3];
        #pragma unroll
        for (int ks = 0; ks < 3; ++ks)
            af[ks] = *(const short8*)&sA[el_base + lr][ks * 32 + lg * 8];

        f32x4 acc1[6];
        #pragma unroll
        for (int nt = 0; nt < 6; ++nt) {
            float bv = rb1[nt];
            acc1[nt] = f32x4{ bv, bv, bv, bv };
        }
        #pragma unroll
        for (int nt = 0; nt < 6; ++nt) {
            short8 bf[3];
            #pragma unroll
            for (int ks = 0; ks < 3; ++ks)
                bf[ks] = *(const short8*)&sW1T[nt * 16 + lr][ks * 32 + lg * 8];
            #pragma unroll
            for (int ks = 0; ks < 3; ++ks)
                acc1[nt] = __builtin_amdgcn_mfma_f32_16x16x32_bf16(
                    af[ks], bf[ks], acc1[nt], 0, 0, 0);
        }

        // ---- ReLU + write H back over sA (D layout: col=lr, row=lg*4+j) ----
        #pragma unroll
        for (int nt = 0; nt < 6; ++nt)
            #pragma unroll
            for (int j = 0; j < 4; ++j)
                sA[el_base + lg * 4 + j][nt * 16 + lr] =
                    f2bf(fmaxf(acc1[nt][j], 0.0f));
        asm volatile("s_waitcnt lgkmcnt(0)" ::: "memory");
        __builtin_amdgcn_sched_barrier(0);

        // ---- GEMM2: O = H @ W2 + b2 (W2 from regs) ----
        short8 a2[3];
        #pragma unroll
        for (int ks = 0; ks < 3; ++ks)
            a2[ks] = *(const short8*)&sA[el_base + lr][ks * 32 + lg * 8];

        f32x4 acc2[4];
        #pragma unroll
        for (int nt = 0; nt < 4; ++nt) {
            float bv = rb2[nt];
            acc2[nt] = f32x4{ bv, bv, bv, bv };
        }
        #pragma unroll
        for (int nt = 0; nt < 4; ++nt)
            #pragma unroll
            for (int ks = 0; ks < 3; ++ks)
                acc2[nt] = __builtin_amdgcn_mfma_f32_16x16x32_bf16(
                    a2[ks], bw2[nt][ks], acc2[nt], 0, 0, 0);

        if constexpr (ATOMIC) {
            int nd[4];
            #pragma unroll
            for (int j = 0; j < 4; ++j)
                nd[j] = ei[N_EDGES + tl * BE + el_base + lg * 4 + j];
            #pragma unroll
            for (int nt = 0; nt < 4; ++nt)
                #pragma unroll
                for (int j = 0; j < 4; ++j)
                    atomicAdd(out + (size_t)nd[j] * OUT_DIM + nt * 16 + lr,
                              acc2[nt][j]);
        } else {
            // ---- bounce O through sA (bf16), then 128-B row store at CSR slot ----
            #pragma unroll
            for (int nt = 0; nt < 4; ++nt)
                #pragma unroll
                for (int j = 0; j < 4; ++j)
                    sA[el_base + lg * 4 + j][nt * 16 + lr] = f2bf(acc2[nt][j]);
            asm volatile("s_waitcnt lgkmcnt(0)" ::: "memory");
            __builtin_amdgcn_sched_barrier(0);
            ushort* dst = temp + (size_t)cpos * OUT_DIM + part * 16;
            short8 v0 = *(const short8*)&sA[el][part * 16];
            short8 v1 = *(const short8*)&sA[el][part * 16 + 8];
            *(short8*)dst = v0;
            *(short8*)(dst + 8) = v1;
        }

        // ---- rotate pipeline registers ----
        if (have) {
            px0 = nx0; px1 = nx1; px2 = nx2; px3 = nx3;
            pe0 = ne0; pe1 = ne1;
            ppos = npos; pdst = ndst;
        }
    }
}

// ---------------------------------------------------------------------------
// Pull: one wave per node; temp rows CSR-contiguous (64 bf16 = 16 uint2/row).
// ---------------------------------------------------------------------------
__global__ __launch_bounds__(256) void pull_kernel(const ushort* __restrict__ temp,
                                                   const int* __restrict__ starts,
                                                   const int* __restrict__ hist,
                                                   float* __restrict__ out) {
    const int wave = threadIdx.x >> 6;
    const int lane = threadIdx.x & 63;
    const int node = blockIdx.x * 4 + wave;
    if (node >= N_NODES) return;
    const int deg = hist[node];
    const int st  = starts[node];
    const int r   = lane >> 4;     // row within quad
    const int g   = lane & 15;     // uint2 index within row
    float sx = 0.f, sy = 0.f, sz = 0.f, sw = 0.f;
    const uint2* base = reinterpret_cast<const uint2*>(temp) + (size_t)st * 16 + g;
    for (int i = r; i < deg; i += 4) {
        uint2 u = base[(size_t)i * 16];
        sx += b2f((ushort)(u.x & 0xFFFFu));
        sy += b2f((ushort)(u.x >> 16));
        sz += b2f((ushort)(u.y & 0xFFFFu));
        sw += b2f((ushort)(u.y >> 16));
    }
    #pragma unroll
    for (int o = 16; o <= 32; o <<= 1) {
        sx += __shfl_xor(sx, o, 64);
        sy += __shfl_xor(sy, o, 64);
        sz += __shfl_xor(sz, o, 64);
        sw += __shfl_xor(sw, o, 64);
    }
    if (r == 0) {
        float inv = 1.0f / fmaxf((float)deg, 1.0f);
        float4 o4 = { sx * inv, sy * inv, sz * inv, sw * inv };
        *reinterpret_cast<float4*>(out + (size_t)node * OUT_DIM + g * 4) = o4;
    }
}

extern "C" void kernel_launch(void* const* d_in, const int* in_sizes, int n_in,
                              void* d_out, int out_size, void* d_ws, size_t ws_size,
                              hipStream_t stream) {
    const float* x  = (const float*)d_in[0];
    const int*   ei = (const int*)d_in[1];
    const float* ea = (const float*)d_in[2];
    const float* W1 = (const float*)d_in[3];
    const float* b1 = (const float*)d_in[4];
    const float* W2 = (const float*)d_in[5];
    const float* b2 = (const float*)d_in[6];
    float* out = (float*)d_out;

    // ws layout: temp[E*64] bf16 | epos[E] | hist[N] | starts[N] | cursor[N] | bsums[64]
    char* ws = (char*)d_ws;
    const size_t tempB    = (size_t)N_EDGES * OUT_DIM * sizeof(ushort); // 102.4 MB
    const size_t eposOff  = tempB;
    const size_t histOff  = eposOff + (size_t)N_EDGES * 4;
    const size_t strOff   = histOff + (size_t)N_NODES * 4;
    const size_t curOff   = strOff + (size_t)N_NODES * 4;
    const size_t bsumOff  = curOff + (size_t)N_NODES * 4;
    const size_t need     = bsumOff + 64 * 4;

    if (ws_size >= need) {
        ushort* temp  = (ushort*)ws;
        int* epos     = (int*)(ws + eposOff);
        int* hist     = (int*)(ws + histOff);
        int* starts   = (int*)(ws + strOff);
        int* cursor   = (int*)(ws + curOff);
        int* bsums    = (int*)(ws + bsumOff);

        hipMemsetAsync(hist, 0, (size_t)N_NODES * 4, stream);
        hist_kernel<<<N_EDGES / 256, 256, 0, stream>>>(ei, hist);
        scan1_kernel<<<SCAN_NB, SCAN_B, 0, stream>>>(hist, starts, bsums);
        scan3_kernel<<<SCAN_NB, SCAN_B, 0, stream>>>(hist, starts, cursor, bsums);
        fill_kernel<<<N_EDGES / 256, 256, 0, stream>>>(ei, cursor, epos);
        edge_mlp_mfma_kernel<false><<<GRID, THREADS, 0, stream>>>(
            x, ei, ea, W1, b1, W2, b2, out, nullptr, temp, epos);
        pull_kernel<<<(N_NODES + 3) / 4, 256, 0, stream>>>(temp, starts, hist, out);
    } else {
        // fallback: atomic scatter path
        float* cnt = (float*)d_ws;  // N_NODES floats
        zero_kernel<<<(N_NODES * OUT_DIM + 255) / 256, 256, 0, stream>>>(out, cnt);
        edge_mlp_mfma_kernel<true><<<GRID, THREADS, 0, stream>>>(
            x, ei, ea, W1, b1, W2, b2, out, cnt, nullptr, nullptr);
        div_kernel<<<(N_NODES * OUT_DIM + 255) / 256, 256, 0, stream>>>(out, cnt);
    }
}

// Round 13
// 280.646 us; speedup vs baseline: 1.3244x; 1.3244x over previous
//
#include <hip/hip_runtime.h>

#define N_EDGES  800000
#define N_NODES  50000
#define IN_DIM   64
#define EDGE_DIM 32
#define HID      96
#define OUT_DIM  64
#define BE       128              // edges per tile
#define PAD      104              // LDS row stride (bf16): 208 B
#define NTILES   (N_EDGES / BE)   // 6250 exactly
#define THREADS  512
#define GRID     768              // 3 blocks/CU, persistent (LDS 46.6 KB)
#define SCAN_B   1024
#define SCAN_NB  ((N_NODES + SCAN_B - 1) / SCAN_B)   // 49

typedef __attribute__((ext_vector_type(8))) short  short8;
typedef __attribute__((ext_vector_type(4))) ushort bf16x4;
typedef __attribute__((ext_vector_type(4))) float  f32x4;

__device__ inline ushort f2bf(float f) {
    union { float f; unsigned u; } v; v.f = f;
    unsigned r = v.u + 0x7FFFu + ((v.u >> 16) & 1u);   // round-to-nearest-even
    return (ushort)(r >> 16);
}
__device__ inline float b2f(ushort u) {
    union { unsigned u; float f; } v; v.u = ((unsigned)u) << 16;
    return v.f;
}

// ---------------------------------------------------------------------------
// CSR-build kernels
// ---------------------------------------------------------------------------
__global__ __launch_bounds__(256) void hist_kernel(const int* __restrict__ ei,
                                                   int* __restrict__ hist) {
    int e = blockIdx.x * 256 + threadIdx.x;
    if (e < N_EDGES) atomicAdd(&hist[ei[N_EDGES + e]], 1);
}

__global__ __launch_bounds__(SCAN_B) void scan1_kernel(const int* __restrict__ hist,
                                                       int* __restrict__ starts,
                                                       int* __restrict__ bsums) {
    __shared__ int buf[2][SCAN_B];
    const int tid = threadIdx.x;
    const int gid = blockIdx.x * SCAN_B + tid;
    int v = (gid < N_NODES) ? hist[gid] : 0;
    int cur = 0;
    buf[0][tid] = v;
    __syncthreads();
    #pragma unroll
    for (int off = 1; off < SCAN_B; off <<= 1) {
        int t = buf[cur][tid] + ((tid >= off) ? buf[cur][tid - off] : 0);
        buf[cur ^ 1][tid] = t;
        __syncthreads();
        cur ^= 1;
    }
    int incl = buf[cur][tid];
    if (gid < N_NODES) starts[gid] = incl;
    if (tid == SCAN_B - 1) bsums[blockIdx.x] = incl;
}

__global__ __launch_bounds__(SCAN_B) void scan3_kernel(const int* __restrict__ hist,
                                                       int* __restrict__ starts,
                                                       int* __restrict__ cursor,
                                                       const int* __restrict__ bsums) {
    __shared__ int s_off;
    if (threadIdx.x < 64) {
        int v = ((int)threadIdx.x < (int)blockIdx.x) ? bsums[threadIdx.x] : 0;
        #pragma unroll
        for (int o = 32; o >= 1; o >>= 1) v += __shfl_xor(v, o, 64);
        if (threadIdx.x == 0) s_off = v;
    }
    __syncthreads();
    const int gid = blockIdx.x * SCAN_B + threadIdx.x;
    if (gid < N_NODES) {
        int e = starts[gid] - hist[gid] + s_off;
        starts[gid] = e;
        cursor[gid] = e;
    }
}

__global__ __launch_bounds__(256) void fill_kernel(const int* __restrict__ ei,
                                                   int* __restrict__ cursor,
                                                   int* __restrict__ epos) {
    int e = blockIdx.x * 256 + threadIdx.x;
    if (e < N_EDGES) {
        int c = ei[N_EDGES + e];
        int p = atomicAdd(&cursor[c], 1);
        epos[e] = p;
    }
}

// ---------------------------------------------------------------------------
// Fallback-path helpers
// ---------------------------------------------------------------------------
__global__ __launch_bounds__(256) void zero_kernel(float* __restrict__ out,
                                                   float* __restrict__ cnt) {
    int i = blockIdx.x * 256 + threadIdx.x;
    if (i < N_NODES * OUT_DIM) out[i] = 0.0f;
    if (i < N_NODES) cnt[i] = 0.0f;
}

__global__ __launch_bounds__(256) void div_kernel(float* __restrict__ out,
                                                  const float* __restrict__ cnt) {
    int i = blockIdx.x * 256 + threadIdx.x;
    if (i < N_NODES * OUT_DIM) {
        float c = cnt[i / OUT_DIM];
        out[i] = out[i] / fmaxf(c, 1.0f);
    }
}

// ---------------------------------------------------------------------------
// Fused gather -> bf16 MFMA MLP (r8 structure + LDS overlay).
// W2T staged into sA rows 0..63, hoisted to regs, sA reused by tile loop.
// LDS 46.6 KB => 3 blocks/CU. __launch_bounds__(512,4): r12's (512,6)
// squeezed VGPR to 40 -> spills (FETCH 138->736 MB). VGPR ~64 needs no cap.
// ---------------------------------------------------------------------------
template <bool ATOMIC>
__global__ __launch_bounds__(THREADS, 4) void edge_mlp_mfma_kernel(
    const float* __restrict__ x,
    const int*   __restrict__ ei,     // [2, E] int32
    const float* __restrict__ ea,
    const float* __restrict__ W1,     // [HID, HID] row-major (k, n)
    const float* __restrict__ b1,
    const float* __restrict__ W2,     // [HID, OUT] row-major (k, n)
    const float* __restrict__ b2,
    float*       __restrict__ out,    // [N, OUT] accumulator (ATOMIC only)
    float*       __restrict__ cnt,    // [N] (ATOMIC only)
    ushort*      __restrict__ temp,   // [E, OUT] bf16 (!ATOMIC only)
    const int*   __restrict__ epos)   // [E] CSR slot (!ATOMIC only)
{
    __shared__ ushort sA[BE][PAD];    // W2T staging (rows 0..63) -> tile buffer
    __shared__ ushort sW1T[HID][PAD]; // W1 transposed: [n][k]

    const int tid  = threadIdx.x;
    const int wave = tid >> 6;
    const int lane = tid & 63;
    const int lr   = lane & 15;
    const int lg   = lane >> 4;
    const int el_base = wave * 16;
    const int el   = el_base + (lane >> 2);   // gather/store row owned by this lane
    const int part = lane & 3;

    // ---- stage weights (bf16, transposed), float4-vectorized ----
    #pragma unroll 2
    for (int i = tid; i < HID * HID / 4; i += THREADS) {
        float4 v = reinterpret_cast<const float4*>(W1)[i];
        int k = (i * 4) / HID, n = (i * 4) % HID;
        sW1T[n + 0][k] = f2bf(v.x); sW1T[n + 1][k] = f2bf(v.y);
        sW1T[n + 2][k] = f2bf(v.z); sW1T[n + 3][k] = f2bf(v.w);
    }
    #pragma unroll 2
    for (int i = tid; i < HID * OUT_DIM / 4; i += THREADS) {   // W2T -> sA rows 0..63
        float4 v = reinterpret_cast<const float4*>(W2)[i];
        int k = (i * 4) / OUT_DIM, n = (i * 4) % OUT_DIM;
        sA[n + 0][k] = f2bf(v.x); sA[n + 1][k] = f2bf(v.y);
        sA[n + 2][k] = f2bf(v.z); sA[n + 3][k] = f2bf(v.w);
    }
    float rb1[6], rb2[4];
    #pragma unroll
    for (int nt = 0; nt < 6; ++nt) rb1[nt] = b1[nt * 16 + lr];
    #pragma unroll
    for (int nt = 0; nt < 4; ++nt) rb2[nt] = b2[nt * 16 + lr];
    __syncthreads();

    // ---- hoist W2 fragments to registers from the sA staging area ----
    short8 bw2[4][3];
    #pragma unroll
    for (int nt = 0; nt < 4; ++nt)
        #pragma unroll
        for (int ks = 0; ks < 3; ++ks)
            bw2[nt][ks] = *(const short8*)&sA[nt * 16 + lr][ks * 32 + lg * 8];
    __syncthreads();   // all waves hoisted before sA is overwritten by gathers

    // ---- prologue: prefetch first tile into registers ----
    float4 px0, px1, px2, px3, pe0, pe1;
    int ppos = 0, pdst = 0;
    int tl = blockIdx.x;
    {
        const int e = tl * BE + el;
        const int src = ei[e];
        if constexpr (ATOMIC) pdst = ei[N_EDGES + e];
        else                  ppos = epos[e];
        const float4* xp = reinterpret_cast<const float4*>(x) + (size_t)src * 16;
        const float4* ep = reinterpret_cast<const float4*>(ea) + (size_t)e * 8;
        px0 = xp[part]; px1 = xp[part + 4]; px2 = xp[part + 8]; px3 = xp[part + 12];
        pe0 = ep[part]; pe1 = ep[part + 4];
    }

    for (; tl < NTILES; tl += GRID) {
        // ---- write the prefetched tile into sA (f = part + 4*i) ----
        {
            bf16x4 w;
            w = bf16x4{ f2bf(px0.x), f2bf(px0.y), f2bf(px0.z), f2bf(px0.w) };
            *(bf16x4*)&sA[el][(part +  0) * 4] = w;
            w = bf16x4{ f2bf(px1.x), f2bf(px1.y), f2bf(px1.z), f2bf(px1.w) };
            *(bf16x4*)&sA[el][(part +  4) * 4] = w;
            w = bf16x4{ f2bf(px2.x), f2bf(px2.y), f2bf(px2.z), f2bf(px2.w) };
            *(bf16x4*)&sA[el][(part +  8) * 4] = w;
            w = bf16x4{ f2bf(px3.x), f2bf(px3.y), f2bf(px3.z), f2bf(px3.w) };
            *(bf16x4*)&sA[el][(part + 12) * 4] = w;
            w = bf16x4{ f2bf(pe0.x), f2bf(pe0.y), f2bf(pe0.z), f2bf(pe0.w) };
            *(bf16x4*)&sA[el][(part + 16) * 4] = w;
            w = bf16x4{ f2bf(pe1.x), f2bf(pe1.y), f2bf(pe1.z), f2bf(pe1.w) };
            *(bf16x4*)&sA[el][(part + 20) * 4] = w;
        }
        const int cpos = ppos, cdst = pdst;
        if constexpr (ATOMIC) {
            if (part == 0) atomicAdd(cnt + cdst, 1.0f);
        }

        // ---- prefetch next tile (flies during the GEMM section) ----
        const int tn = tl + GRID;
        const bool have = (tn < NTILES);
        float4 nx0, nx1, nx2, nx3, ne0, ne1;
        int npos = 0, ndst = 0;
        if (have) {
            const int e = tn * BE + el;
            const int src = ei[e];
            if constexpr (ATOMIC) ndst = ei[N_EDGES + e];
            else                  npos = epos[e];
            const float4* xp = reinterpret_cast<const float4*>(x) + (size_t)src * 16;
            const float4* ep = reinterpret_cast<const float4*>(ea) + (size_t)e * 8;
            nx0 = xp[part]; nx1 = xp[part + 4]; nx2 = xp[part + 8]; nx3 = xp[part + 12];
            ne0 = ep[part]; ne1 = ep[part + 4];
        }

        asm volatile("s_waitcnt lgkmcnt(0)" ::: "memory");
        __builtin_amdgcn_sched_barrier(0);

        // ---- GEMM1: H = relu(A @ W1 + b1) ----
        short8 af[3];
        #pragma unroll
        for (int ks = 0; ks < 3; ++ks)
            af[ks] = *(const short8*)&sA[el_base + lr][ks * 32 + lg * 8];

        f32x4 acc1[6];
        #pragma unroll
        for (int nt = 0; nt < 6; ++nt) {
            float bv = rb1[nt];
            acc1[nt] = f32x4{ bv, bv, bv, bv };
        }
        #pragma unroll
        for (int nt = 0; nt < 6; ++nt) {
            short8 bf[3];
            #pragma unroll
            for (int ks = 0; ks < 3; ++ks)
                bf[ks] = *(const short8*)&sW1T[nt * 16 + lr][ks * 32 + lg * 8];
            #pragma unroll
            for (int ks = 0; ks < 3; ++ks)
                acc1[nt] = __builtin_amdgcn_mfma_f32_16x16x32_bf16(
                    af[ks], bf[ks], acc1[nt], 0, 0, 0);
        }

        // ---- ReLU + write H back over sA (D layout: col=lr, row=lg*4+j) ----
        #pragma unroll
        for (int nt = 0; nt < 6; ++nt)
            #pragma unroll
            for (int j = 0; j < 4; ++j)
                sA[el_base + lg * 4 + j][nt * 16 + lr] =
                    f2bf(fmaxf(acc1[nt][j], 0.0f));
        asm volatile("s_waitcnt lgkmcnt(0)" ::: "memory");
        __builtin_amdgcn_sched_barrier(0);

        // ---- GEMM2: O = H @ W2 + b2 (W2 from regs) ----
        short8 a2[3];
        #pragma unroll
        for (int ks = 0; ks < 3; ++ks)
            a2[ks] = *(const short8*)&sA[el_base + lr][ks * 32 + lg * 8];

        f32x4 acc2[4];
        #pragma unroll
        for (int nt = 0; nt < 4; ++nt) {
            float bv = rb2[nt];
            acc2[nt] = f32x4{ bv, bv, bv, bv };
        }
        #pragma unroll
        for (int nt = 0; nt < 4; ++nt)
            #pragma unroll
            for (int ks = 0; ks < 3; ++ks)
                acc2[nt] = __builtin_amdgcn_mfma_f32_16x16x32_bf16(
                    a2[ks], bw2[nt][ks], acc2[nt], 0, 0, 0);

        if constexpr (ATOMIC) {
            int nd[4];
            #pragma unroll
            for (int j = 0; j < 4; ++j)
                nd[j] = ei[N_EDGES + tl * BE + el_base + lg * 4 + j];
            #pragma unroll
            for (int nt = 0; nt < 4; ++nt)
                #pragma unroll
                for (int j = 0; j < 4; ++j)
                    atomicAdd(out + (size_t)nd[j] * OUT_DIM + nt * 16 + lr,
                              acc2[nt][j]);
        } else {
            // ---- bounce O through sA (bf16), then 128-B row store at CSR slot ----
            #pragma unroll
            for (int nt = 0; nt < 4; ++nt)
                #pragma unroll
                for (int j = 0; j < 4; ++j)
                    sA[el_base + lg * 4 + j][nt * 16 + lr] = f2bf(acc2[nt][j]);
            asm volatile("s_waitcnt lgkmcnt(0)" ::: "memory");
            __builtin_amdgcn_sched_barrier(0);
            ushort* dst = temp + (size_t)cpos * OUT_DIM + part * 16;
            short8 v0 = *(const short8*)&sA[el][part * 16];
            short8 v1 = *(const short8*)&sA[el][part * 16 + 8];
            *(short8*)dst = v0;
            *(short8*)(dst + 8) = v1;
        }

        // ---- rotate pipeline registers ----
        if (have) {
            px0 = nx0; px1 = nx1; px2 = nx2; px3 = nx3;
            pe0 = ne0; pe1 = ne1;
            ppos = npos; pdst = ndst;
        }
    }
}

// ---------------------------------------------------------------------------
// Pull: one wave per node; temp rows CSR-contiguous (64 bf16 = 16 uint2/row).
// ---------------------------------------------------------------------------
__global__ __launch_bounds__(256) void pull_kernel(const ushort* __restrict__ temp,
                                                   const int* __restrict__ starts,
                                                   const int* __restrict__ hist,
                                                   float* __restrict__ out) {
    const int wave = threadIdx.x >> 6;
    const int lane = threadIdx.x & 63;
    const int node = blockIdx.x * 4 + wave;
    if (node >= N_NODES) return;
    const int deg = hist[node];
    const int st  = starts[node];
    const int r   = lane >> 4;     // row within quad
    const int g   = lane & 15;     // uint2 index within row
    float sx = 0.f, sy = 0.f, sz = 0.f, sw = 0.f;
    const uint2* base = reinterpret_cast<const uint2*>(temp) + (size_t)st * 16 + g;
    for (int i = r; i < deg; i += 4) {
        uint2 u = base[(size_t)i * 16];
        sx += b2f((ushort)(u.x & 0xFFFFu));
        sy += b2f((ushort)(u.x >> 16));
        sz += b2f((ushort)(u.y & 0xFFFFu));
        sw += b2f((ushort)(u.y >> 16));
    }
    #pragma unroll
    for (int o = 16; o <= 32; o <<= 1) {
        sx += __shfl_xor(sx, o, 64);
        sy += __shfl_xor(sy, o, 64);
        sz += __shfl_xor(sz, o, 64);
        sw += __shfl_xor(sw, o, 64);
    }
    if (r == 0) {
        float inv = 1.0f / fmaxf((float)deg, 1.0f);
        float4 o4 = { sx * inv, sy * inv, sz * inv, sw * inv };
        *reinterpret_cast<float4*>(out + (size_t)node * OUT_DIM + g * 4) = o4;
    }
}

extern "C" void kernel_launch(void* const* d_in, const int* in_sizes, int n_in,
                              void* d_out, int out_size, void* d_ws, size_t ws_size,
                              hipStream_t stream) {
    const float* x  = (const float*)d_in[0];
    const int*   ei = (const int*)d_in[1];
    const float* ea = (const float*)d_in[2];
    const float* W1 = (const float*)d_in[3];
    const float* b1 = (const float*)d_in[4];
    const float* W2 = (const float*)d_in[5];
    const float* b2 = (const float*)d_in[6];
    float* out = (float*)d_out;

    // ws layout: temp[E*64] bf16 | epos[E] | hist[N] | starts[N] | cursor[N] | bsums[64]
    char* ws = (char*)d_ws;
    const size_t tempB    = (size_t)N_EDGES * OUT_DIM * sizeof(ushort); // 102.4 MB
    const size_t eposOff  = tempB;
    const size_t histOff  = eposOff + (size_t)N_EDGES * 4;
    const size_t strOff   = histOff + (size_t)N_NODES * 4;
    const size_t curOff   = strOff + (size_t)N_NODES * 4;
    const size_t bsumOff  = curOff + (size_t)N_NODES * 4;
    const size_t need     = bsumOff + 64 * 4;

    if (ws_size >= need) {
        ushort* temp  = (ushort*)ws;
        int* epos     = (int*)(ws + eposOff);
        int* hist     = (int*)(ws + histOff);
        int* starts   = (int*)(ws + strOff);
        int* cursor   = (int*)(ws + curOff);
        int* bsums    = (int*)(ws + bsumOff);

        hipMemsetAsync(hist, 0, (size_t)N_NODES * 4, stream);
        hist_kernel<<<N_EDGES / 256, 256, 0, stream>>>(ei, hist);
        scan1_kernel<<<SCAN_NB, SCAN_B, 0, stream>>>(hist, starts, bsums);
        scan3_kernel<<<SCAN_NB, SCAN_B, 0, stream>>>(hist, starts, cursor, bsums);
        fill_kernel<<<N_EDGES / 256, 256, 0, stream>>>(ei, cursor, epos);
        edge_mlp_mfma_kernel<false><<<GRID, THREADS, 0, stream>>>(
            x, ei, ea, W1, b1, W2, b2, out, nullptr, temp, epos);
        pull_kernel<<<(N_NODES + 3) / 4, 256, 0, stream>>>(temp, starts, hist, out);
    } else {
        // fallback: atomic scatter path
        float* cnt = (float*)d_ws;  // N_NODES floats
        zero_kernel<<<(N_NODES * OUT_DIM + 255) / 256, 256, 0, stream>>>(out, cnt);
        edge_mlp_mfma_kernel<true><<<GRID, THREADS, 0, stream>>>(
            x, ei, ea, W1, b1, W2, b2, out, cnt, nullptr, nullptr);
        div_kernel<<<(N_NODES * OUT_DIM + 255) / 256, 256, 0, stream>>>(out, cnt);
    }
}

// Round 14
// 226.354 us; speedup vs baseline: 1.6420x; 1.2399x over previous
//
#include <hip/hip_runtime.h>

#define N_EDGES  800000
#define N_NODES  50000
#define IN_DIM   64
#define EDGE_DIM 32
#define HID      96
#define OUT_DIM  64
#define BE       128              // edges per tile
#define PAD      104              // LDS row stride (bf16): 208 B
#define NTILES   (N_EDGES / BE)   // 6250 exactly
#define THREADS  512
#define GRID     512              // 2 blocks/CU, persistent — r8 sweet spot, do not change
#define SCAN_B   1024
#define SCAN_NB  ((N_NODES + SCAN_B - 1) / SCAN_B)   // 49

typedef __attribute__((ext_vector_type(8))) short  short8;
typedef __attribute__((ext_vector_type(4))) ushort bf16x4;
typedef __attribute__((ext_vector_type(4))) float  f32x4;

__device__ inline ushort f2bf(float f) {
    union { float f; unsigned u; } v; v.f = f;
    unsigned r = v.u + 0x7FFFu + ((v.u >> 16) & 1u);   // round-to-nearest-even
    return (ushort)(r >> 16);
}
__device__ inline float b2f(ushort u) {
    union { unsigned u; float f; } v; v.u = ((unsigned)u) << 16;
    return v.f;
}

// ---------------------------------------------------------------------------
// CSR-build kernels. hist also records each edge's arrival rank in epos
// (the same atomic it already did) so fill needs NO atomics / cursor.
// ---------------------------------------------------------------------------
__global__ __launch_bounds__(256) void hist_kernel(const int* __restrict__ ei,
                                                   int* __restrict__ hist,
                                                   int* __restrict__ epos) {
    int e = blockIdx.x * 256 + threadIdx.x;
    if (e < N_EDGES) epos[e] = atomicAdd(&hist[ei[N_EDGES + e]], 1);
}

__global__ __launch_bounds__(SCAN_B) void scan1_kernel(const int* __restrict__ hist,
                                                       int* __restrict__ starts,
                                                       int* __restrict__ bsums) {
    __shared__ int buf[2][SCAN_B];
    const int tid = threadIdx.x;
    const int gid = blockIdx.x * SCAN_B + tid;
    int v = (gid < N_NODES) ? hist[gid] : 0;
    int cur = 0;
    buf[0][tid] = v;
    __syncthreads();
    #pragma unroll
    for (int off = 1; off < SCAN_B; off <<= 1) {
        int t = buf[cur][tid] + ((tid >= off) ? buf[cur][tid - off] : 0);
        buf[cur ^ 1][tid] = t;
        __syncthreads();
        cur ^= 1;
    }
    int incl = buf[cur][tid];
    if (gid < N_NODES) starts[gid] = incl;
    if (tid == SCAN_B - 1) bsums[blockIdx.x] = incl;
}

__global__ __launch_bounds__(SCAN_B) void scan3_kernel(const int* __restrict__ hist,
                                                       int* __restrict__ starts,
                                                       const int* __restrict__ bsums) {
    __shared__ int s_off;
    if (threadIdx.x < 64) {
        int v = ((int)threadIdx.x < (int)blockIdx.x) ? bsums[threadIdx.x] : 0;
        #pragma unroll
        for (int o = 32; o >= 1; o >>= 1) v += __shfl_xor(v, o, 64);
        if (threadIdx.x == 0) s_off = v;
    }
    __syncthreads();
    const int gid = blockIdx.x * SCAN_B + threadIdx.x;
    if (gid < N_NODES) starts[gid] = starts[gid] - hist[gid] + s_off;
}

// fill: epos[e] = starts[dst] + rank[e]; pure loads + one store, no atomics
__global__ __launch_bounds__(256) void fill_kernel(const int* __restrict__ ei,
                                                   const int* __restrict__ starts,
                                                   int* __restrict__ epos) {
    int e = blockIdx.x * 256 + threadIdx.x;
    if (e < N_EDGES) epos[e] = starts[ei[N_EDGES + e]] + epos[e];
}

// ---------------------------------------------------------------------------
// Fallback-path helpers
// ---------------------------------------------------------------------------
__global__ __launch_bounds__(256) void zero_kernel(float* __restrict__ out,
                                                   float* __restrict__ cnt) {
    int i = blockIdx.x * 256 + threadIdx.x;
    if (i < N_NODES * OUT_DIM) out[i] = 0.0f;
    if (i < N_NODES) cnt[i] = 0.0f;
}

__global__ __launch_bounds__(256) void div_kernel(float* __restrict__ out,
                                                  const float* __restrict__ cnt) {
    int i = blockIdx.x * 256 + threadIdx.x;
    if (i < N_NODES * OUT_DIM) {
        float c = cnt[i / OUT_DIM];
        out[i] = out[i] / fmaxf(c, 1.0f);
    }
}

// ---------------------------------------------------------------------------
// Fused gather -> bf16 MFMA MLP — EXACT r8 structure (78 µs measured:
// FETCH 138 MB, WRITE 100 MB, 2 blocks/CU). Perturbations of occupancy,
// ordering, or gather shape all regressed (r9-r13); keep verbatim.
// ---------------------------------------------------------------------------
template <bool ATOMIC>
__global__ __launch_bounds__(THREADS, 4) void edge_mlp_mfma_kernel(
    const float* __restrict__ x,
    const int*   __restrict__ ei,     // [2, E] int32
    const float* __restrict__ ea,
    const float* __restrict__ W1,     // [HID, HID] row-major (k, n)
    const float* __restrict__ b1,
    const float* __restrict__ W2,     // [HID, OUT] row-major (k, n)
    const float* __restrict__ b2,
    float*       __restrict__ out,    // [N, OUT] accumulator (ATOMIC only)
    float*       __restrict__ cnt,    // [N] (ATOMIC only)
    ushort*      __restrict__ temp,   // [E, OUT] bf16 (!ATOMIC only)
    const int*   __restrict__ epos)   // [E] CSR slot (!ATOMIC only)
{
    __shared__ ushort sA[BE][PAD];        // input tile, then H, then O (reused)
    __shared__ ushort sW1T[HID][PAD];     // W1 transposed: [n][k]
    __shared__ ushort sW2T[OUT_DIM][PAD]; // W2 transposed: [n][k] (staging only)

    const int tid  = threadIdx.x;
    const int wave = tid >> 6;
    const int lane = tid & 63;
    const int lr   = lane & 15;
    const int lg   = lane >> 4;
    const int el_base = wave * 16;
    const int el   = el_base + (lane >> 2);   // gather/store row owned by this lane
    const int part = lane & 3;

    // ---- stage weights (bf16, transposed), float4-vectorized ----
    #pragma unroll 2
    for (int i = tid; i < HID * HID / 4; i += THREADS) {
        float4 v = reinterpret_cast<const float4*>(W1)[i];
        int k = (i * 4) / HID, n = (i * 4) % HID;
        sW1T[n + 0][k] = f2bf(v.x); sW1T[n + 1][k] = f2bf(v.y);
        sW1T[n + 2][k] = f2bf(v.z); sW1T[n + 3][k] = f2bf(v.w);
    }
    #pragma unroll 2
    for (int i = tid; i < HID * OUT_DIM / 4; i += THREADS) {
        float4 v = reinterpret_cast<const float4*>(W2)[i];
        int k = (i * 4) / OUT_DIM, n = (i * 4) % OUT_DIM;
        sW2T[n + 0][k] = f2bf(v.x); sW2T[n + 1][k] = f2bf(v.y);
        sW2T[n + 2][k] = f2bf(v.z); sW2T[n + 3][k] = f2bf(v.w);
    }
    float rb1[6], rb2[4];
    #pragma unroll
    for (int nt = 0; nt < 6; ++nt) rb1[nt] = b1[nt * 16 + lr];
    #pragma unroll
    for (int nt = 0; nt < 4; ++nt) rb2[nt] = b2[nt * 16 + lr];
    __syncthreads();

    // ---- hoist W2 fragments into registers (one-time; 12 x short8) ----
    short8 bw2[4][3];
    #pragma unroll
    for (int nt = 0; nt < 4; ++nt)
        #pragma unroll
        for (int ks = 0; ks < 3; ++ks)
            bw2[nt][ks] = *(const short8*)&sW2T[nt * 16 + lr][ks * 32 + lg * 8];

    // ---- prologue: prefetch first tile into registers ----
    float4 px0, px1, px2, px3, pe0, pe1;
    int ppos = 0, pdst = 0;
    int tl = blockIdx.x;
    {
        const int e = tl * BE + el;
        const int src = ei[e];
        if constexpr (ATOMIC) pdst = ei[N_EDGES + e];
        else                  ppos = epos[e];
        const float4* xp = reinterpret_cast<const float4*>(x) + (size_t)src * 16;
        const float4* ep = reinterpret_cast<const float4*>(ea) + (size_t)e * 8;
        px0 = xp[part]; px1 = xp[part + 4]; px2 = xp[part + 8]; px3 = xp[part + 12];
        pe0 = ep[part]; pe1 = ep[part + 4];
    }

    for (; tl < NTILES; tl += GRID) {
        // ---- write the prefetched tile into sA (f = part + 4*i) ----
        {
            bf16x4 w;
            w = bf16x4{ f2bf(px0.x), f2bf(px0.y), f2bf(px0.z), f2bf(px0.w) };
            *(bf16x4*)&sA[el][(part +  0) * 4] = w;
            w = bf16x4{ f2bf(px1.x), f2bf(px1.y), f2bf(px1.z), f2bf(px1.w) };
            *(bf16x4*)&sA[el][(part +  4) * 4] = w;
            w = bf16x4{ f2bf(px2.x), f2bf(px2.y), f2bf(px2.z), f2bf(px2.w) };
            *(bf16x4*)&sA[el][(part +  8) * 4] = w;
            w = bf16x4{ f2bf(px3.x), f2bf(px3.y), f2bf(px3.z), f2bf(px3.w) };
            *(bf16x4*)&sA[el][(part + 12) * 4] = w;
            w = bf16x4{ f2bf(pe0.x), f2bf(pe0.y), f2bf(pe0.z), f2bf(pe0.w) };
            *(bf16x4*)&sA[el][(part + 16) * 4] = w;
            w = bf16x4{ f2bf(pe1.x), f2bf(pe1.y), f2bf(pe1.z), f2bf(pe1.w) };
            *(bf16x4*)&sA[el][(part + 20) * 4] = w;
        }
        const int cpos = ppos, cdst = pdst;
        if constexpr (ATOMIC) {
            if (part == 0) atomicAdd(cnt + cdst, 1.0f);
        }

        // ---- prefetch next tile (flies during the GEMM section) ----
        const int tn = tl + GRID;
        const bool have = (tn < NTILES);
        float4 nx0, nx1, nx2, nx3, ne0, ne1;
        int npos = 0, ndst = 0;
        if (have) {
            const int e = tn * BE + el;
            const int src = ei[e];
            if constexpr (ATOMIC) ndst = ei[N_EDGES + e];
            else                  npos = epos[e];
            const float4* xp = reinterpret_cast<const float4*>(x) + (size_t)src * 16;
            const float4* ep = reinterpret_cast<const float4*>(ea) + (size_t)e * 8;
            nx0 = xp[part]; nx1 = xp[part + 4]; nx2 = xp[part + 8]; nx3 = xp[part + 12];
            ne0 = ep[part]; ne1 = ep[part + 4];
        }

        asm volatile("s_waitcnt lgkmcnt(0)" ::: "memory");
        __builtin_amdgcn_sched_barrier(0);

        // ---- GEMM1: H = relu(A @ W1 + b1) ----
        short8 af[3];
        #pragma unroll
        for (int ks = 0; ks < 3; ++ks)
            af[ks] = *(const short8*)&sA[el_base + lr][ks * 32 + lg * 8];

        f32x4 acc1[6];
        #pragma unroll
        for (int nt = 0; nt < 6; ++nt) {
            float bv = rb1[nt];
            acc1[nt] = f32x4{ bv, bv, bv, bv };
        }
        #pragma unroll
        for (int nt = 0; nt < 6; ++nt) {
            short8 bf[3];
            #pragma unroll
            for (int ks = 0; ks < 3; ++ks)
                bf[ks] = *(const short8*)&sW1T[nt * 16 + lr][ks * 32 + lg * 8];
            #pragma unroll
            for (int ks = 0; ks < 3; ++ks)
                acc1[nt] = __builtin_amdgcn_mfma_f32_16x16x32_bf16(
                    af[ks], bf[ks], acc1[nt], 0, 0, 0);
        }

        // ---- ReLU + write H back over sA (D layout: col=lr, row=lg*4+j) ----
        #pragma unroll
        for (int nt = 0; nt < 6; ++nt)
            #pragma unroll
            for (int j = 0; j < 4; ++j)
                sA[el_base + lg * 4 + j][nt * 16 + lr] =
                    f2bf(fmaxf(acc1[nt][j], 0.0f));
        asm volatile("s_waitcnt lgkmcnt(0)" ::: "memory");
        __builtin_amdgcn_sched_barrier(0);

        // ---- GEMM2: O = H @ W2 + b2 (W2 from regs) ----
        short8 a2[3];
        #pragma unroll
        for (int ks = 0; ks < 3; ++ks)
            a2[ks] = *(const short8*)&sA[el_base + lr][ks * 32 + lg * 8];

        f32x4 acc2[4];
        #pragma unroll
        for (int nt = 0; nt < 4; ++nt) {
            float bv = rb2[nt];
            acc2[nt] = f32x4{ bv, bv, bv, bv };
        }
        #pragma unroll
        for (int nt = 0; nt < 4; ++nt)
            #pragma unroll
            for (int ks = 0; ks < 3; ++ks)
                acc2[nt] = __builtin_amdgcn_mfma_f32_16x16x32_bf16(
                    a2[ks], bw2[nt][ks], acc2[nt], 0, 0, 0);

        if constexpr (ATOMIC) {
            int nd[4];
            #pragma unroll
            for (int j = 0; j < 4; ++j)
                nd[j] = ei[N_EDGES + tl * BE + el_base + lg * 4 + j];
            #pragma unroll
            for (int nt = 0; nt < 4; ++nt)
                #pragma unroll
                for (int j = 0; j < 4; ++j)
                    atomicAdd(out + (size_t)nd[j] * OUT_DIM + nt * 16 + lr,
                              acc2[nt][j]);
        } else {
            // ---- bounce O through sA (bf16), then 128-B row store at CSR slot ----
            #pragma unroll
            for (int nt = 0; nt < 4; ++nt)
                #pragma unroll
                for (int j = 0; j < 4; ++j)
                    sA[el_base + lg * 4 + j][nt * 16 + lr] = f2bf(acc2[nt][j]);
            asm volatile("s_waitcnt lgkmcnt(0)" ::: "memory");
            __builtin_amdgcn_sched_barrier(0);
            ushort* dst = temp + (size_t)cpos * OUT_DIM + part * 16;
            short8 v0 = *(const short8*)&sA[el][part * 16];
            short8 v1 = *(const short8*)&sA[el][part * 16 + 8];
            *(short8*)dst = v0;
            *(short8*)(dst + 8) = v1;
        }

        // ---- rotate pipeline registers ----
        if (have) {
            px0 = nx0; px1 = nx1; px2 = nx2; px3 = nx3;
            pe0 = ne0; pe1 = ne1;
            ppos = npos; pdst = ndst;
        }
    }
}

// ---------------------------------------------------------------------------
// Pull: one wave per node; temp rows CSR-contiguous (64 bf16 = 16 uint2/row).
// ---------------------------------------------------------------------------
__global__ __launch_bounds__(256) void pull_kernel(const ushort* __restrict__ temp,
                                                   const int* __restrict__ starts,
                                                   const int* __restrict__ hist,
                                                   float* __restrict__ out) {
    const int wave = threadIdx.x >> 6;
    const int lane = threadIdx.x & 63;
    const int node = blockIdx.x * 4 + wave;
    if (node >= N_NODES) return;
    const int deg = hist[node];
    const int st  = starts[node];
    const int r   = lane >> 4;     // row within quad
    const int g   = lane & 15;     // uint2 index within row
    float sx = 0.f, sy = 0.f, sz = 0.f, sw = 0.f;
    const uint2* base = reinterpret_cast<const uint2*>(temp) + (size_t)st * 16 + g;
    for (int i = r; i < deg; i += 4) {
        uint2 u = base[(size_t)i * 16];
        sx += b2f((ushort)(u.x & 0xFFFFu));
        sy += b2f((ushort)(u.x >> 16));
        sz += b2f((ushort)(u.y & 0xFFFFu));
        sw += b2f((ushort)(u.y >> 16));
    }
    #pragma unroll
    for (int o = 16; o <= 32; o <<= 1) {
        sx += __shfl_xor(sx, o, 64);
        sy += __shfl_xor(sy, o, 64);
        sz += __shfl_xor(sz, o, 64);
        sw += __shfl_xor(sw, o, 64);
    }
    if (r == 0) {
        float inv = 1.0f / fmaxf((float)deg, 1.0f);
        float4 o4 = { sx * inv, sy * inv, sz * inv, sw * inv };
        *reinterpret_cast<float4*>(out + (size_t)node * OUT_DIM + g * 4) = o4;
    }
}

extern "C" void kernel_launch(void* const* d_in, const int* in_sizes, int n_in,
                              void* d_out, int out_size, void* d_ws, size_t ws_size,
                              hipStream_t stream) {
    const float* x  = (const float*)d_in[0];
    const int*   ei = (const int*)d_in[1];
    const float* ea = (const float*)d_in[2];
    const float* W1 = (const float*)d_in[3];
    const float* b1 = (const float*)d_in[4];
    const float* W2 = (const float*)d_in[5];
    const float* b2 = (const float*)d_in[6];
    float* out = (float*)d_out;

    // ws layout: temp[E*64] bf16 | epos[E] | hist[N] | starts[N] | bsums[64]
    char* ws = (char*)d_ws;
    const size_t tempB    = (size_t)N_EDGES * OUT_DIM * sizeof(ushort); // 102.4 MB
    const size_t eposOff  = tempB;
    const size_t histOff  = eposOff + (size_t)N_EDGES * 4;
    const size_t strOff   = histOff + (size_t)N_NODES * 4;
    const size_t bsumOff  = strOff + (size_t)N_NODES * 4;
    const size_t need     = bsumOff + 64 * 4;

    if (ws_size >= need) {
        ushort* temp  = (ushort*)ws;
        int* epos     = (int*)(ws + eposOff);
        int* hist     = (int*)(ws + histOff);
        int* starts   = (int*)(ws + strOff);
        int* bsums    = (int*)(ws + bsumOff);

        hipMemsetAsync(hist, 0, (size_t)N_NODES * 4, stream);
        hist_kernel<<<N_EDGES / 256, 256, 0, stream>>>(ei, hist, epos);
        scan1_kernel<<<SCAN_NB, SCAN_B, 0, stream>>>(hist, starts, bsums);
        scan3_kernel<<<SCAN_NB, SCAN_B, 0, stream>>>(hist, starts, bsums);
        fill_kernel<<<N_EDGES / 256, 256, 0, stream>>>(ei, starts, epos);
        edge_mlp_mfma_kernel<false><<<GRID, THREADS, 0, stream>>>(
            x, ei, ea, W1, b1, W2, b2, out, nullptr, temp, epos);
        pull_kernel<<<(N_NODES + 3) / 4, 256, 0, stream>>>(temp, starts, hist, out);
    } else {
        // fallback: atomic scatter path
        float* cnt = (float*)d_ws;  // N_NODES floats
        zero_kernel<<<(N_NODES * OUT_DIM + 255) / 256, 256, 0, stream>>>(out, cnt);
        edge_mlp_mfma_kernel<true><<<GRID, THREADS, 0, stream>>>(
            x, ei, ea, W1, b1, W2, b2, out, cnt, nullptr, nullptr);
        div_kernel<<<(N_NODES * OUT_DIM + 255) / 256, 256, 0, stream>>>(out, cnt);
    }
}

// Round 15
// 174.413 us; speedup vs baseline: 2.1310x; 1.2978x over previous
//
#include <hip/hip_runtime.h>

#define N_EDGES  800000
#define N_NODES  50000
#define IN_DIM   64
#define EDGE_DIM 32
#define HID      96
#define OUT_DIM  64
#define BE       128              // edges per tile
#define PAD      104              // LDS row stride (bf16): 208 B; frag reads land 2-way (free)
#define NTILES   (N_EDGES / BE)   // 6250 exactly
#define THREADS  512
#define GRID     512              // 2 blocks/CU, persistent
#define SCAN_B   1024
#define SCAN_NB  ((N_NODES + SCAN_B - 1) / SCAN_B)   // 49

typedef __attribute__((ext_vector_type(8))) short  short8;
typedef __attribute__((ext_vector_type(4))) ushort bf16x4;
typedef __attribute__((ext_vector_type(4))) float  f32x4;

__device__ inline ushort f2bf(float f) {
    union { float f; unsigned u; } v; v.f = f;
    unsigned r = v.u + 0x7FFFu + ((v.u >> 16) & 1u);   // round-to-nearest-even
    return (ushort)(r >> 16);
}
__device__ inline float b2f(ushort u) {
    union { unsigned u; float f; } v; v.u = ((unsigned)u) << 16;
    return v.f;
}

// ---------------------------------------------------------------------------
// CSR-build kernels (exact round-8 versions)
// ---------------------------------------------------------------------------
__global__ __launch_bounds__(256) void hist_kernel(const int* __restrict__ ei,
                                                   int* __restrict__ hist) {
    int e = blockIdx.x * 256 + threadIdx.x;
    if (e < N_EDGES) atomicAdd(&hist[ei[N_EDGES + e]], 1);
}

__global__ __launch_bounds__(SCAN_B) void scan1_kernel(const int* __restrict__ hist,
                                                       int* __restrict__ starts,
                                                       int* __restrict__ bsums) {
    __shared__ int buf[2][SCAN_B];
    const int tid = threadIdx.x;
    const int gid = blockIdx.x * SCAN_B + tid;
    int v = (gid < N_NODES) ? hist[gid] : 0;
    int cur = 0;
    buf[0][tid] = v;
    __syncthreads();
    #pragma unroll
    for (int off = 1; off < SCAN_B; off <<= 1) {
        int t = buf[cur][tid] + ((tid >= off) ? buf[cur][tid - off] : 0);
        buf[cur ^ 1][tid] = t;
        __syncthreads();
        cur ^= 1;
    }
    int incl = buf[cur][tid];
    if (gid < N_NODES) starts[gid] = incl;
    if (tid == SCAN_B - 1) bsums[blockIdx.x] = incl;
}

__global__ __launch_bounds__(SCAN_B) void scan3_kernel(const int* __restrict__ hist,
                                                       int* __restrict__ starts,
                                                       int* __restrict__ cursor,
                                                       const int* __restrict__ bsums) {
    __shared__ int s_off;
    if (threadIdx.x < 64) {
        int v = ((int)threadIdx.x < (int)blockIdx.x) ? bsums[threadIdx.x] : 0;
        #pragma unroll
        for (int o = 32; o >= 1; o >>= 1) v += __shfl_xor(v, o, 64);
        if (threadIdx.x == 0) s_off = v;
    }
    __syncthreads();
    const int gid = blockIdx.x * SCAN_B + threadIdx.x;
    if (gid < N_NODES) {
        int e = starts[gid] - hist[gid] + s_off;
        starts[gid] = e;
        cursor[gid] = e;
    }
}

__global__ __launch_bounds__(256) void fill_kernel(const int* __restrict__ ei,
                                                   int* __restrict__ cursor,
                                                   int* __restrict__ epos) {
    int e = blockIdx.x * 256 + threadIdx.x;
    if (e < N_EDGES) {
        int c = ei[N_EDGES + e];
        int p = atomicAdd(&cursor[c], 1);
        epos[e] = p;
    }
}

// ---------------------------------------------------------------------------
// Fallback-path helpers
// ---------------------------------------------------------------------------
__global__ __launch_bounds__(256) void zero_kernel(float* __restrict__ out,
                                                   float* __restrict__ cnt) {
    int i = blockIdx.x * 256 + threadIdx.x;
    if (i < N_NODES * OUT_DIM) out[i] = 0.0f;
    if (i < N_NODES) cnt[i] = 0.0f;
}

__global__ __launch_bounds__(256) void div_kernel(float* __restrict__ out,
                                                  const float* __restrict__ cnt) {
    int i = blockIdx.x * 256 + threadIdx.x;
    if (i < N_NODES * OUT_DIM) {
        float c = cnt[i / OUT_DIM];
        out[i] = out[i] / fmaxf(c, 1.0f);
    }
}

// ---------------------------------------------------------------------------
// Fused gather -> bf16 MFMA MLP, depth-1 software-pipelined gather.
// EXACT round-8 artifact (174 µs total; MLP 78 µs @ FETCH 138 MB).
// ---------------------------------------------------------------------------
template <bool ATOMIC>
__global__ __launch_bounds__(THREADS, 4) void edge_mlp_mfma_kernel(
    const float* __restrict__ x,
    const int*   __restrict__ ei,     // [2, E] int32
    const float* __restrict__ ea,
    const float* __restrict__ W1,     // [HID, HID] row-major (k, n)
    const float* __restrict__ b1,
    const float* __restrict__ W2,     // [HID, OUT] row-major (k, n)
    const float* __restrict__ b2,
    float*       __restrict__ out,    // [N, OUT] accumulator (ATOMIC only)
    float*       __restrict__ cnt,    // [N] (ATOMIC only)
    ushort*      __restrict__ temp,   // [E, OUT] bf16 (!ATOMIC only)
    const int*   __restrict__ epos)   // [E] CSR slot (!ATOMIC only)
{
    __shared__ ushort sA[BE][PAD];        // input tile, then H, then O (reused)
    __shared__ ushort sW1T[HID][PAD];     // W1 transposed: [n][k]
    __shared__ ushort sW2T[OUT_DIM][PAD]; // W2 transposed: [n][k]

    const int tid  = threadIdx.x;
    const int wave = tid >> 6;
    const int lane = tid & 63;
    const int lr   = lane & 15;
    const int lg   = lane >> 4;
    const int el_base = wave * 16;
    const int el   = el_base + (lane >> 2);   // gather/store row owned by this lane
    const int part = lane & 3;

    // ---- stage weights (bf16, transposed), float4-vectorized ----
    #pragma unroll 2
    for (int i = tid; i < HID * HID / 4; i += THREADS) {
        float4 v = reinterpret_cast<const float4*>(W1)[i];
        int k = (i * 4) / HID, n = (i * 4) % HID;
        sW1T[n + 0][k] = f2bf(v.x); sW1T[n + 1][k] = f2bf(v.y);
        sW1T[n + 2][k] = f2bf(v.z); sW1T[n + 3][k] = f2bf(v.w);
    }
    #pragma unroll 2
    for (int i = tid; i < HID * OUT_DIM / 4; i += THREADS) {
        float4 v = reinterpret_cast<const float4*>(W2)[i];
        int k = (i * 4) / OUT_DIM, n = (i * 4) % OUT_DIM;
        sW2T[n + 0][k] = f2bf(v.x); sW2T[n + 1][k] = f2bf(v.y);
        sW2T[n + 2][k] = f2bf(v.z); sW2T[n + 3][k] = f2bf(v.w);
    }
    float rb1[6], rb2[4];
    #pragma unroll
    for (int nt = 0; nt < 6; ++nt) rb1[nt] = b1[nt * 16 + lr];
    #pragma unroll
    for (int nt = 0; nt < 4; ++nt) rb2[nt] = b2[nt * 16 + lr];
    __syncthreads();

    // ---- prologue: prefetch first tile into registers ----
    float4 px0, px1, px2, px3, pe0, pe1;
    int ppos = 0, pdst = 0;
    int tl = blockIdx.x;
    {
        const int e = tl * BE + el;
        const int src = ei[e];
        if constexpr (ATOMIC) pdst = ei[N_EDGES + e];
        else                  ppos = epos[e];
        const float4* xp = reinterpret_cast<const float4*>(x) + (size_t)src * 16;
        const float4* ep = reinterpret_cast<const float4*>(ea) + (size_t)e * 8;
        px0 = xp[part]; px1 = xp[part + 4]; px2 = xp[part + 8]; px3 = xp[part + 12];
        pe0 = ep[part]; pe1 = ep[part + 4];
    }

    for (; tl < NTILES; tl += GRID) {
        // ---- write the prefetched tile into sA (f = part + 4*i) ----
        {
            bf16x4 w;
            w = bf16x4{ f2bf(px0.x), f2bf(px0.y), f2bf(px0.z), f2bf(px0.w) };
            *(bf16x4*)&sA[el][(part +  0) * 4] = w;
            w = bf16x4{ f2bf(px1.x), f2bf(px1.y), f2bf(px1.z), f2bf(px1.w) };
            *(bf16x4*)&sA[el][(part +  4) * 4] = w;
            w = bf16x4{ f2bf(px2.x), f2bf(px2.y), f2bf(px2.z), f2bf(px2.w) };
            *(bf16x4*)&sA[el][(part +  8) * 4] = w;
            w = bf16x4{ f2bf(px3.x), f2bf(px3.y), f2bf(px3.z), f2bf(px3.w) };
            *(bf16x4*)&sA[el][(part + 12) * 4] = w;
            w = bf16x4{ f2bf(pe0.x), f2bf(pe0.y), f2bf(pe0.z), f2bf(pe0.w) };
            *(bf16x4*)&sA[el][(part + 16) * 4] = w;
            w = bf16x4{ f2bf(pe1.x), f2bf(pe1.y), f2bf(pe1.z), f2bf(pe1.w) };
            *(bf16x4*)&sA[el][(part + 20) * 4] = w;
        }
        const int cpos = ppos, cdst = pdst;
        if constexpr (ATOMIC) {
            if (part == 0) atomicAdd(cnt + cdst, 1.0f);
        }

        // ---- prefetch next tile (flies during the GEMM section) ----
        const int tn = tl + GRID;
        const bool have = (tn < NTILES);
        float4 nx0, nx1, nx2, nx3, ne0, ne1;
        int npos = 0, ndst = 0;
        if (have) {
            const int e = tn * BE + el;
            const int src = ei[e];
            if constexpr (ATOMIC) ndst = ei[N_EDGES + e];
            else                  npos = epos[e];
            const float4* xp = reinterpret_cast<const float4*>(x) + (size_t)src * 16;
            const float4* ep = reinterpret_cast<const float4*>(ea) + (size_t)e * 8;
            nx0 = xp[part]; nx1 = xp[part + 4]; nx2 = xp[part + 8]; nx3 = xp[part + 12];
            ne0 = ep[part]; ne1 = ep[part + 4];
        }

        asm volatile("s_waitcnt lgkmcnt(0)" ::: "memory");
        __builtin_amdgcn_sched_barrier(0);

        // ---- GEMM1: H = relu(A @ W1 + b1) ----
        short8 af[3];
        #pragma unroll
        for (int ks = 0; ks < 3; ++ks)
            af[ks] = *(const short8*)&sA[el_base + lr][ks * 32 + lg * 8];

        f32x4 acc1[6];
        #pragma unroll
        for (int nt = 0; nt < 6; ++nt) {
            float bv = rb1[nt];
            acc1[nt] = f32x4{ bv, bv, bv, bv };
        }
        #pragma unroll
        for (int nt = 0; nt < 6; ++nt) {
            short8 bf[3];
            #pragma unroll
            for (int ks = 0; ks < 3; ++ks)
                bf[ks] = *(const short8*)&sW1T[nt * 16 + lr][ks * 32 + lg * 8];
            #pragma unroll
            for (int ks = 0; ks < 3; ++ks)
                acc1[nt] = __builtin_amdgcn_mfma_f32_16x16x32_bf16(
                    af[ks], bf[ks], acc1[nt], 0, 0, 0);
        }

        // ---- ReLU + write H back over sA (D layout: col=lr, row=lg*4+j) ----
        #pragma unroll
        for (int nt = 0; nt < 6; ++nt)
            #pragma unroll
            for (int j = 0; j < 4; ++j)
                sA[el_base + lg * 4 + j][nt * 16 + lr] =
                    f2bf(fmaxf(acc1[nt][j], 0.0f));
        asm volatile("s_waitcnt lgkmcnt(0)" ::: "memory");
        __builtin_amdgcn_sched_barrier(0);

        // ---- GEMM2: O = H @ W2 + b2 ----
        short8 a2[3];
        #pragma unroll
        for (int ks = 0; ks < 3; ++ks)
            a2[ks] = *(const short8*)&sA[el_base + lr][ks * 32 + lg * 8];

        f32x4 acc2[4];
        #pragma unroll
        for (int nt = 0; nt < 4; ++nt) {
            float bv = rb2[nt];
            acc2[nt] = f32x4{ bv, bv, bv, bv };
        }
        #pragma unroll
        for (int nt = 0; nt < 4; ++nt) {
            short8 bf[3];
            #pragma unroll
            for (int ks = 0; ks < 3; ++ks)
                bf[ks] = *(const short8*)&sW2T[nt * 16 + lr][ks * 32 + lg * 8];
            #pragma unroll
            for (int ks = 0; ks < 3; ++ks)
                acc2[nt] = __builtin_amdgcn_mfma_f32_16x16x32_bf16(
                    a2[ks], bf[ks], acc2[nt], 0, 0, 0);
        }

        if constexpr (ATOMIC) {
            int nd[4];
            #pragma unroll
            for (int j = 0; j < 4; ++j)
                nd[j] = ei[N_EDGES + tl * BE + el_base + lg * 4 + j];
            #pragma unroll
            for (int nt = 0; nt < 4; ++nt)
                #pragma unroll
                for (int j = 0; j < 4; ++j)
                    atomicAdd(out + (size_t)nd[j] * OUT_DIM + nt * 16 + lr,
                              acc2[nt][j]);
        } else {
            // ---- bounce O through sA (bf16), then 128-B row store at CSR slot ----
            #pragma unroll
            for (int nt = 0; nt < 4; ++nt)
                #pragma unroll
                for (int j = 0; j < 4; ++j)
                    sA[el_base + lg * 4 + j][nt * 16 + lr] = f2bf(acc2[nt][j]);
            asm volatile("s_waitcnt lgkmcnt(0)" ::: "memory");
            __builtin_amdgcn_sched_barrier(0);
            ushort* dst = temp + (size_t)cpos * OUT_DIM + part * 16;
            short8 v0 = *(const short8*)&sA[el][part * 16];
            short8 v1 = *(const short8*)&sA[el][part * 16 + 8];
            *(short8*)dst = v0;
            *(short8*)(dst + 8) = v1;
        }

        // ---- rotate pipeline registers ----
        if (have) {
            px0 = nx0; px1 = nx1; px2 = nx2; px3 = nx3;
            pe0 = ne0; pe1 = ne1;
            ppos = npos; pdst = ndst;
        }
    }
}

// ---------------------------------------------------------------------------
// Pull: one wave per node; temp rows CSR-contiguous (64 bf16 = 16 uint2/row).
// ---------------------------------------------------------------------------
__global__ __launch_bounds__(256) void pull_kernel(const ushort* __restrict__ temp,
                                                   const int* __restrict__ starts,
                                                   const int* __restrict__ hist,
                                                   float* __restrict__ out) {
    const int wave = threadIdx.x >> 6;
    const int lane = threadIdx.x & 63;
    const int node = blockIdx.x * 4 + wave;
    if (node >= N_NODES) return;
    const int deg = hist[node];
    const int st  = starts[node];
    const int r   = lane >> 4;     // row within quad
    const int g   = lane & 15;     // uint2 index within row
    float sx = 0.f, sy = 0.f, sz = 0.f, sw = 0.f;
    const uint2* base = reinterpret_cast<const uint2*>(temp) + (size_t)st * 16 + g;
    for (int i = r; i < deg; i += 4) {
        uint2 u = base[(size_t)i * 16];
        sx += b2f((ushort)(u.x & 0xFFFFu));
        sy += b2f((ushort)(u.x >> 16));
        sz += b2f((ushort)(u.y & 0xFFFFu));
        sw += b2f((ushort)(u.y >> 16));
    }
    #pragma unroll
    for (int o = 16; o <= 32; o <<= 1) {
        sx += __shfl_xor(sx, o, 64);
        sy += __shfl_xor(sy, o, 64);
        sz += __shfl_xor(sz, o, 64);
        sw += __shfl_xor(sw, o, 64);
    }
    if (r == 0) {
        float inv = 1.0f / fmaxf((float)deg, 1.0f);
        float4 o4 = { sx * inv, sy * inv, sz * inv, sw * inv };
        *reinterpret_cast<float4*>(out + (size_t)node * OUT_DIM + g * 4) = o4;
    }
}

extern "C" void kernel_launch(void* const* d_in, const int* in_sizes, int n_in,
                              void* d_out, int out_size, void* d_ws, size_t ws_size,
                              hipStream_t stream) {
    const float* x  = (const float*)d_in[0];
    const int*   ei = (const int*)d_in[1];
    const float* ea = (const float*)d_in[2];
    const float* W1 = (const float*)d_in[3];
    const float* b1 = (const float*)d_in[4];
    const float* W2 = (const float*)d_in[5];
    const float* b2 = (const float*)d_in[6];
    float* out = (float*)d_out;

    // ws layout: temp[E*64] bf16 | epos[E] | hist[N] | starts[N] | cursor[N] | bsums[64]
    char* ws = (char*)d_ws;
    const size_t tempB    = (size_t)N_EDGES * OUT_DIM * sizeof(ushort); // 102.4 MB
    const size_t eposOff  = tempB;
    const size_t histOff  = eposOff + (size_t)N_EDGES * 4;
    const size_t strOff   = histOff + (size_t)N_NODES * 4;
    const size_t curOff   = strOff + (size_t)N_NODES * 4;
    const size_t bsumOff  = curOff + (size_t)N_NODES * 4;
    const size_t need     = bsumOff + 64 * 4;

    if (ws_size >= need) {
        ushort* temp  = (ushort*)ws;
        int* epos     = (int*)(ws + eposOff);
        int* hist     = (int*)(ws + histOff);
        int* starts   = (int*)(ws + strOff);
        int* cursor   = (int*)(ws + curOff);
        int* bsums    = (int*)(ws + bsumOff);

        hipMemsetAsync(hist, 0, (size_t)N_NODES * 4, stream);
        hist_kernel<<<N_EDGES / 256, 256, 0, stream>>>(ei, hist);
        scan1_kernel<<<SCAN_NB, SCAN_B, 0, stream>>>(hist, starts, bsums);
        scan3_kernel<<<SCAN_NB, SCAN_B, 0, stream>>>(hist, starts, cursor, bsums);
        fill_kernel<<<N_EDGES / 256, 256, 0, stream>>>(ei, cursor, epos);
        edge_mlp_mfma_kernel<false><<<GRID, THREADS, 0, stream>>>(
            x, ei, ea, W1, b1, W2, b2, out, nullptr, temp, epos);
        pull_kernel<<<(N_NODES + 3) / 4, 256, 0, stream>>>(temp, starts, hist, out);
    } else {
        // fallback: atomic scatter path
        float* cnt = (float*)d_ws;  // N_NODES floats
        zero_kernel<<<(N_NODES * OUT_DIM + 255) / 256, 256, 0, stream>>>(out, cnt);
        edge_mlp_mfma_kernel<true><<<GRID, THREADS, 0, stream>>>(
            x, ei, ea, W1, b1, W2, b2, out, cnt, nullptr, nullptr);
        div_kernel<<<(N_NODES * OUT_DIM + 255) / 256, 256, 0, stream>>>(out, cnt);
    }
}